// Round 7
// baseline (98.927 us; speedup 1.0000x reference)
//
#include <hip/hip_runtime.h>

#define BB 16
#define NN 300
#define PP 100
#define LL 32
#define HH 768
#define WW 768
#define BAND 16                 // rows per band-block
#define NBAND (HH / BAND)       // 48
#define PSTR 772                // LDS row stride in floats (16B-aligned)

__device__ __forceinline__ float relu_f(float x) { return fmaxf(x, 0.f); }

// ---------------------------------------------------------------------------
// Single fused kernel. Grid = BB*NBAND = 768 blocks (exactly 3/CU) x 512 thr.
//  Phase 0: per-block box metadata (conf softmax + pixel coords) in LDS.
//  Phase A: 16-row band row-prefix sums into LDS (lane-run scan, R5-proven).
//  Phase B: thread-per-box partial box-sums over band rows -> detPartial.
//  band==0 blocks also compute plate-IoU + OCR terms for their batch.
//  Ticket 1 (per-batch): last of 48 blocks sums partials in fixed order.
//  Ticket 2 (global): last of 16 finalizers does the final combine.
// All FP reductions fixed-order => deterministic; atomics are control only.
// ---------------------------------------------------------------------------
__global__ __launch_bounds__(512, 6) void k_all(
        const float* __restrict__ seg,
        const float* __restrict__ det_boxes,
        const float* __restrict__ logits,
        const float* __restrict__ plate_boxes,
        const float* __restrict__ plate_conf,
        const float* __restrict__ ocr,
        int*   __restrict__ cnts,        // [0..15] per-batch, [16] global (pre-zeroed)
        float* __restrict__ detPartial,  // [BB][NBAND][NN]
        float* __restrict__ detBatch,    // [BB]
        float* __restrict__ platePart,   // [BB]
        float* __restrict__ plateCnt,    // [BB]
        float* __restrict__ ocrPart,     // [BB]
        float* __restrict__ out) {
    const int blk  = blockIdx.x;
    const int b    = blk / NBAND;
    const int band = blk % NBAND;
    const int y0   = band * BAND;
    const int t    = threadIdx.x;
    const int wave = t >> 6, lane = t & 63;

    __shared__ float P[BAND * PSTR];     // 49408 B (aliased by plate arrays later)
    __shared__ int   metaX[NN];          // x1 | ((x2-1)<<16), 0 if invalid
    __shared__ int   metaY[NN];          // y1 | (y2<<16),     0 if invalid
    __shared__ float confA[NN];
    __shared__ float redW[8];
    __shared__ int   redI[8];
    __shared__ int   anyFlag;
    __shared__ int   lastFlag;

    // ---- Phase 0: box metadata -------------------------------------------
    for (int j = t; j < NN; j += 512) {
        const float* lg = logits + ((size_t)b * NN + j) * 7;
        float m = lg[0];
        #pragma unroll
        for (int i = 1; i < 7; ++i) m = fmaxf(m, lg[i]);
        float sum = 0.f;
        #pragma unroll
        for (int i = 0; i < 7; ++i) sum += expf(lg[i] - m);
        float conf = 1.f / sum;
        confA[j] = conf;

        const float* bxp = det_boxes + ((size_t)b * NN + j) * 4;
        float cx = bxp[0], cy = bxp[1], w = bxp[2], h = bxp[3];
        int x1 = (int)floorf((cx - w * 0.5f) * (float)WW);
        int y1 = (int)floorf((cy - h * 0.5f) * (float)HH);
        int x2 = (int)floorf((cx + w * 0.5f) * (float)WW);
        int y2 = (int)floorf((cy + h * 0.5f) * (float)HH);
        x1 = min(max(x1, 0), WW - 1); y1 = min(max(y1, 0), HH - 1);
        x2 = min(max(x2, 0), WW - 1); y2 = min(max(y2, 0), HH - 1);
        bool valid = (conf >= 0.3f) && (x2 > x1) && (y2 > y1);
        metaX[j] = valid ? (x1 | ((x2 - 1) << 16)) : 0;
        metaY[j] = valid ? (y1 | (y2 << 16)) : 0;
    }

    // ---- Phase A: 8 waves x 2 rows, lane-run scan (12 floats/lane) --------
    #pragma unroll
    for (int rr = 0; rr < 2; ++rr) {
        const int r = wave * 2 + rr;
        const int y = y0 + r;
        const float* p1 = seg + ((size_t)(b * 3 + 1) * HH + y) * WW + 12 * lane;
        const float* p2 = seg + ((size_t)(b * 3 + 2) * HH + y) * WW + 12 * lane;
        float4 A0 = *(const float4*)(p1);
        float4 A1 = *(const float4*)(p1 + 4);
        float4 A2 = *(const float4*)(p1 + 8);
        float4 B0 = *(const float4*)(p2);
        float4 B1 = *(const float4*)(p2 + 4);
        float4 B2 = *(const float4*)(p2 + 8);
        float r0  = B0.x - A0.x;
        float r1  = r0 + (B0.y - A0.y);
        float r2  = r1 + (B0.z - A0.z);
        float r3  = r2 + (B0.w - A0.w);
        float r4  = r3 + (B1.x - A1.x);
        float r5  = r4 + (B1.y - A1.y);
        float r6  = r5 + (B1.z - A1.z);
        float r7  = r6 + (B1.w - A1.w);
        float r8  = r7 + (B2.x - A2.x);
        float r9  = r8 + (B2.y - A2.y);
        float r10 = r9 + (B2.z - A2.z);
        float r11 = r10 + (B2.w - A2.w);
        float total = r11;
        float incl = total;
        #pragma unroll
        for (int d = 1; d < 64; d <<= 1) {
            float u = __shfl_up(incl, d, 64);
            if (lane >= d) incl += u;
        }
        float excl = incl - total;
        float* Prow = P + r * PSTR + 12 * lane;
        float4 w0 = { r0 + excl, r1 + excl, r2  + excl, r3  + excl };
        float4 w1 = { r4 + excl, r5 + excl, r6  + excl, r7  + excl };
        float4 w2 = { r8 + excl, r9 + excl, r10 + excl, r11 + excl };
        *(float4*)(Prow)     = w0;
        *(float4*)(Prow + 4) = w1;
        *(float4*)(Prow + 8) = w2;
    }
    __syncthreads();

    // ---- Phase B+C: per-box band partials, contiguous write ---------------
    float* outp = detPartial + ((size_t)b * NBAND + band) * NN;
    for (int j = t; j < NN; j += 512) {
        int mx = metaX[j], my = metaY[j];
        int y1 = my & 0xffff, y2 = my >> 16;
        int lo = max(y1, y0), hi = min(y2, y0 + BAND);
        float acc = 0.f;
        if (lo < hi) {
            int x1 = mx & 0xffff, x2m1 = mx >> 16;
            const float* Pp = P + (lo - y0) * PSTR;
            if (x1 > 0) {
                for (int r = lo; r < hi; ++r, Pp += PSTR) acc += Pp[x2m1] - Pp[x1 - 1];
            } else {
                for (int r = lo; r < hi; ++r, Pp += PSTR) acc += Pp[x2m1];
            }
        }
        outp[j] = acc;
    }

    // ---- band==0 blocks: plate IoU + OCR for batch b ----------------------
    if (band == 0) {
        if (t == 0) anyFlag = 0;
        __syncthreads();                       // P free after Phase B; alias it
        float* vx1 = P;
        float* vy1 = P + NN;
        float* vx2 = P + 2 * NN;
        float* vy2 = P + 3 * NN;
        float* va  = P + 4 * NN;
        for (int j = t; j < NN; j += 512) {
            const float* bxp = det_boxes + ((size_t)b * NN + j) * 4;
            float cx = bxp[0], cy = bxp[1], w = bxp[2], h = bxp[3];
            float x1 = cx - w * 0.5f, y1 = cy - h * 0.5f;
            float x2 = cx + w * 0.5f, y2 = cy + h * 0.5f;
            vx1[j] = x1; vy1[j] = y1; vx2[j] = x2; vy2[j] = y2;
            va[j] = (x2 - x1) * (y2 - y1);
            if (confA[j] > 0.3f) anyFlag = 1;   // benign race, all write 1
        }
        __syncthreads();

        float term = 0.f; int pv = 0; float pcf = -1e30f;
        if (t < PP) {
            const float* bxp = plate_boxes + ((size_t)b * PP + t) * 4;
            float cx = bxp[0], cy = bxp[1], w = bxp[2], h = bxp[3];
            float px1 = cx - w * 0.5f, py1 = cy - h * 0.5f;
            float px2 = cx + w * 0.5f, py2 = cy + h * 0.5f;
            float a1 = (px2 - px1) * (py2 - py1);
            pcf = plate_conf[b * PP + t];
            pv = (pcf > 0.3f) ? 1 : 0;
            float max_iou = -1.f;
            for (int j = 0; j < NN; ++j) {
                if (confA[j] > 0.3f) {
                    float ltx = fmaxf(px1, vx1[j]);
                    float lty = fmaxf(py1, vy1[j]);
                    float rbx = fminf(px2, vx2[j]);
                    float rby = fminf(py2, vy2[j]);
                    float iw = fmaxf(rbx - ltx, 0.f);
                    float ih = fmaxf(rby - lty, 0.f);
                    float inter = iw * ih;
                    float uni = a1 + va[j] - inter;
                    float iou = inter / (uni + 1e-8f);
                    max_iou = fmaxf(max_iou, iou);
                }
            }
            if (pv) term = relu_f(0.5f - max_iou) * pcf;
        }
        // reduce term-sum (f32) and pv-count (int): wave shuffle + fixed order
        {
            float v = term;
            #pragma unroll
            for (int d = 32; d > 0; d >>= 1) v += __shfl_down(v, d, 64);
            int iv = pv;
            #pragma unroll
            for (int d = 32; d > 0; d >>= 1) iv += __shfl_down(iv, d, 64);
            if (lane == 0) { redW[wave] = v; redI[wave] = iv; }
        }
        __syncthreads();
        float termsum; int cnt;
        if (t == 0) {
            float s = 0.f; int c2 = 0;
            #pragma unroll
            for (int w2 = 0; w2 < 8; ++w2) { s += redW[w2]; c2 += redI[w2]; }
            termsum = s; cnt = c2;
            platePart[b] = (cnt > 0 && anyFlag) ? termsum : 0.f;
            plateCnt[b]  = (float)cnt;
        }
        __syncthreads();
        // max_plate over all P plates
        {
            float mv = (t < PP) ? plate_conf[b * PP + t] : -1e30f;
            #pragma unroll
            for (int d = 32; d > 0; d >>= 1) mv = fmaxf(mv, __shfl_down(mv, d, 64));
            if (lane == 0) redW[wave] = mv;
        }
        __syncthreads();
        // avg_ocr
        {
            float osum = 0.f;
            if (t < LL) {
                const float* op = ocr + ((size_t)b * LL + t) * 37;
                float m = op[0];
                #pragma unroll
                for (int i = 1; i < 37; ++i) m = fmaxf(m, op[i]);
                osum = m;
            }
            #pragma unroll
            for (int d = 32; d > 0; d >>= 1) osum += __shfl_down(osum, d, 64);
            if (t == 0) {
                float max_plate = -1e30f;
                #pragma unroll
                for (int w2 = 0; w2 < 8; ++w2) max_plate = fmaxf(max_plate, redW[w2]);
                float avg_ocr = osum / (float)LL;
                ocrPart[b] = (avg_ocr > 0.7f) ? relu_f(avg_ocr - max_plate) : 0.f;
            }
        }
    }

    // ---- Ticket 1: per-batch last block finalizes det term ----------------
    __syncthreads();
    if (t == 0) {
        __threadfence();                       // release: partials visible
        int old = atomicAdd(&cnts[b], 1);
        lastFlag = (old == NBAND - 1) ? 1 : 0;
    }
    __syncthreads();
    if (!lastFlag) return;
    __threadfence();                           // acquire: see other blocks' writes

    float contrib = 0.f;
    if (t < NN) {
        int my = metaY[t];
        if (my) {
            const float* pp = detPartial + (size_t)b * NBAND * NN + t;
            float s = 0.f;
            for (int g = 0; g < NBAND; ++g) s += pp[(size_t)g * NN];
            int mx = metaX[t];
            int x1 = mx & 0xffff, x2 = (mx >> 16) + 1;
            int y1 = my & 0xffff, y2 = my >> 16;
            float area = (float)((y2 - y1) * (x2 - x1));
            contrib = relu_f(s / area) * confA[t];
        }
    }
    {
        float v = contrib;
        #pragma unroll
        for (int d = 32; d > 0; d >>= 1) v += __shfl_down(v, d, 64);
        if (lane == 0) redW[wave] = v;
    }
    __syncthreads();
    if (t == 0) {
        float ds = 0.f;
        #pragma unroll
        for (int w2 = 0; w2 < 8; ++w2) ds += redW[w2];
        detBatch[b] = ds;
        __threadfence();                       // release detBatch
        int old = atomicAdd(&cnts[16], 1);
        lastFlag = (old == BB - 1) ? 1 : 0;
    }
    __syncthreads();
    if (!lastFlag) return;

    // ---- Ticket 2: global combine (fixed order, f64) ----------------------
    if (t == 0) {
        __threadfence();                       // acquire
        double ds = 0.0, ps = 0.0, pc = 0.0, os = 0.0;
        for (int b2 = 0; b2 < BB; ++b2) {
            ds += (double)detBatch[b2];
            ps += (double)platePart[b2];
            pc += (double)plateCnt[b2];
            os += (double)ocrPart[b2];
        }
        float det_seg   = (float)ds / (float)(BB * NN);
        float plate_det = (float)ps / fmaxf((float)pc, 1.f);
        float ocr_plate = (float)os / (float)BB;
        out[0] = 0.1f * det_seg + 0.1f * plate_det + 0.1f * ocr_plate;
    }
}

extern "C" void kernel_launch(void* const* d_in, const int* in_sizes, int n_in,
                              void* d_out, int out_size, void* d_ws, size_t ws_size,
                              hipStream_t stream) {
    const float* det_boxes   = (const float*)d_in[0];
    const float* det_logits  = (const float*)d_in[1];
    const float* seg_masks   = (const float*)d_in[2];
    const float* plate_boxes = (const float*)d_in[3];
    const float* plate_conf  = (const float*)d_in[4];
    const float* ocr_probs   = (const float*)d_in[5];
    float* out = (float*)d_out;

    // workspace layout: counters first (zeroed each call), then buffers
    int*   cnts       = (int*)d_ws;                            // 32 ints (use 17)
    float* detPartial = (float*)d_ws + 32;                     // BB*NBAND*NN
    float* detBatch   = detPartial + (size_t)BB * NBAND * NN;  // 16
    float* platePart  = detBatch + BB;                         // 16
    float* plateCnt   = platePart + BB;                        // 16
    float* ocrPart    = plateCnt + BB;                         // 16

    hipMemsetAsync(cnts, 0, 128, stream);
    k_all<<<BB * NBAND, 512, 0, stream>>>(seg_masks, det_boxes, det_logits,
                                          plate_boxes, plate_conf, ocr_probs,
                                          cnts, detPartial, detBatch,
                                          platePart, plateCnt, ocrPart, out);
}